// Round 8
// baseline (745.620 us; speedup 1.0000x reference)
//
#include <hip/hip_runtime.h>
#include <hip/hip_bf16.h>

#define BB 128   // batch
#define TT 512   // time
#define EE 100   // embed dim
#define HH 128   // hidden
#define KK 12    // tags
#define VV 50257 // vocab

typedef short bf16x8 __attribute__((ext_vector_type(8)));
typedef float f32x4  __attribute__((ext_vector_type(4)));

__device__ __forceinline__ unsigned short f2bf(float x) {
  __hip_bfloat16 h = __float2bfloat16(x);
  return *reinterpret_cast<unsigned short*>(&h);
}

__device__ __forceinline__ bf16x8 load8_bf(const float* p) {
  float4 a = *reinterpret_cast<const float4*>(p);
  float4 b = *reinterpret_cast<const float4*>(p + 4);
  bf16x8 r;
  r[0] = (short)f2bf(a.x); r[1] = (short)f2bf(a.y);
  r[2] = (short)f2bf(a.z); r[3] = (short)f2bf(a.w);
  r[4] = (short)f2bf(b.x); r[5] = (short)f2bf(b.y);
  r[6] = (short)f2bf(b.z); r[7] = (short)f2bf(b.w);
  return r;
}

// scalar loads with zero-padding past n (E=100 -> K=128 pad)
__device__ __forceinline__ bf16x8 load8_bf_pad(const float* row, int k0, int n) {
  bf16x8 r;
  #pragma unroll
  for (int i = 0; i < 8; ++i) {
    unsigned short v = 0;
    if (k0 + i < n) v = f2bf(row[k0 + i]);
    r[i] = (short)v;
  }
  return r;
}

// fast sigmoid / tanh: v_exp2 + v_rcp
__device__ __forceinline__ float sigr(float x) {
  float e = __builtin_amdgcn_exp2f(x * -1.44269504f);
  return __builtin_amdgcn_rcpf(1.0f + e);
}
__device__ __forceinline__ float tanhr(float x) {
  float e = __builtin_amdgcn_exp2f(x * -2.88539008f);
  return __fmaf_rn(2.0f, __builtin_amdgcn_rcpf(1.0f + e), -1.0f);
}

// ushort index of (row b, col k) in A-frag-ordered tile (lane-linear for mfma)
__device__ __forceinline__ int frag_idx(int b, int k) {
  return ((k >> 5) << 9) + ((b + (((k >> 3) & 3) << 4)) << 3) + (k & 7);
}

// ---------------------------------------------------------------------------
// Kernel 0: one-time precast of embedding table to bf16, [V][128] ushorts,
// cols 100..127 zeroed (K-pad). One thread per 16B chunk.
// ---------------------------------------------------------------------------
__global__ __launch_bounds__(256) void precast_kernel(
    const float* __restrict__ embed, unsigned short* __restrict__ ebf)
{
  int id = blockIdx.x * 256 + threadIdx.x;
  if (id >= VV * 16) return;
  int v = id >> 4, g = id & 15;
  const float* row = embed + (size_t)v * EE;
  bf16x8 o;
  #pragma unroll
  for (int i = 0; i < 8; ++i) {
    int k = g * 8 + i;
    o[i] = (short)((k < EE) ? f2bf(row[k]) : (unsigned short)0);
  }
  *reinterpret_cast<bf16x8*>(ebf + (size_t)id * 8) = o;
}

// ---------------------------------------------------------------------------
// Fused kernel. grid = 8 blocks (16 batches) x 512 threads (8 waves).
// Wave w: gate GEMM for e-strip [16w,16w+16), 4 col-tiles = gates {i,f,g,o}
// -> cell update fully lane-local. Wave 0 additionally: emission MFMA (lag 1)
// -> ering. Waves 4-7 additionally: x staging (bf16 table, pure copies) and
// Viterbi DP (lag 2, reads ering across the step barrier).
// ---------------------------------------------------------------------------
__global__ __launch_bounds__(512, 2) void lstm_crf_fused(
    const int* __restrict__ sent, const unsigned short* __restrict__ ebf,
    const float* __restrict__ Wih, const float* __restrict__ Whh,
    const float* __restrict__ bih, const float* __restrict__ bhh,
    const float* __restrict__ h0, const float* __restrict__ c0,
    const float* __restrict__ Wtag, const float* __restrict__ btag,
    const float* __restrict__ trans, float* __restrict__ out)
{
  __shared__ unsigned char bp[256 * 192];                  // 48 KB nibble-packed
  __shared__ __align__(16) unsigned short hfrag[2][2048];  // 8 KB h, frag order
  __shared__ __align__(16) unsigned short xfrag[2][2048];  // 8 KB x, frag order
  __shared__ __align__(16) float vit[16 * 16];             // trellis
  __shared__ __align__(16) float trl[KK * 16];             // trl[j*16+i]=trans[i][j]
  __shared__ __align__(16) float ering[2][16 * 16];        // emission ring

  const int bg  = blockIdx.x;
  const int tid = threadIdx.x;
  const int w   = tid >> 6;         // wave 0..7
  const int l   = tid & 63;
  const int c   = l & 15;           // MFMA col within tile
  const int q   = l >> 4;           // row group (b = q*4+r)

  // ---- weights: 4 gate-tiles {i,f,g,o} of e-strip [16w,16w+16) ----
  const int ew = 16 * w + c;
  bf16x8 wh[4][4], wx[4][4];
  float biasv[4];
  #pragma unroll
  for (int tt = 0; tt < 4; ++tt) {
    const int gcol = tt * HH + ew;
    biasv[tt] = bih[gcol] + bhh[gcol];
    #pragma unroll
    for (int kt = 0; kt < 4; ++kt) {
      const int k0 = kt * 32 + q * 8;
      wh[tt][kt] = load8_bf(Whh + (size_t)gcol * HH + k0);
      wx[tt][kt] = load8_bf_pad(Wih + (size_t)gcol * EE, k0, EE);
    }
  }

  // ---- cell state: lane (q,c) holds c for (b=q*4+r, e=ew) ----
  float cst[4];
  #pragma unroll
  for (int r = 0; r < 4; ++r)
    cst[r] = c0[(size_t)(bg * 16 + q * 4 + r) * HH + ew];

  // ---- emission weight fragments (wave 0 only uses them) ----
  bf16x8 we[4];
  #pragma unroll
  for (int kt = 0; kt < 4; ++kt) {
    #pragma unroll
    for (int i = 0; i < 8; ++i) we[kt][i] = 0;
  }
  float bt = 0.f;
  if (w == 0 && c < KK) {
    #pragma unroll
    for (int kt = 0; kt < 4; ++kt)
      we[kt] = load8_bf(Wtag + (size_t)c * HH + kt * 32 + q * 8);
    bt = btag[c];
  }

  // ---- h0 -> hfrag[0] ----
  for (int idx = tid; idx < 2048; idx += 512) {
    int b = idx >> 7, k = idx & 127;
    hfrag[0][frag_idx(b, k)] = f2bf(h0[(size_t)(bg * 16 + b) * HH + k]);
  }
  // ---- transitions (transposed, padded) -> LDS ----
  if (tid < KK * KK) {
    int i = tid / KK, jj = tid - i * KK;
    trl[jj * 16 + i] = trans[tid];
  }

  // ---- x staging (waves 4-7): one 16B chunk per lane, pure copy ----
  const bool stg = (w >= 4);
  const int sid = tid & 255;
  const int sb = sid >> 4, g = sid & 15;
  const int* sentb = sent + (size_t)(bg * 16 + sb) * TT;
  const int xoff = ((g >> 2) << 9) + ((((g & 3) << 4) + sb) << 3);
  if (stg) {   // x(0) direct
    const unsigned short* src = ebf + (size_t)sentb[0] * 128 + g * 8;
    *reinterpret_cast<int4*>(&xfrag[0][xoff]) =
        *reinterpret_cast<const int4*>(src);
  }
  int4 xv = {0, 0, 0, 0};
  if (stg)     // issue loads for x(1)
    xv = *reinterpret_cast<const int4*>(ebf + (size_t)sentb[1] * 128 + g * 8);

  // h write-back base
  const int hw_off = frag_idx(q * 4, ew);

  int nib = 0;
  __syncthreads();

  for (int s = 0; s <= TT + 1; ++s) {
    const int rb = s & 1;

    // A fragments: h(s-1) tile (lane-linear, conflict-free)
    bf16x8 ha[4];
    if (s <= TT) {
      const bf16x8* hr = reinterpret_cast<const bf16x8*>(&hfrag[rb][0]) + l;
      #pragma unroll
      for (int kt = 0; kt < 4; ++kt) ha[kt] = hr[kt * 64];
    }

    // ---- wave 0: emissions E(t=s-1) -> ering ----
    if (w == 0 && s >= 1 && s <= TT) {
      f32x4 accE = {0.f, 0.f, 0.f, 0.f};
      #pragma unroll
      for (int kt = 0; kt < 4; ++kt)
        accE = __builtin_amdgcn_mfma_f32_16x16x32_bf16(ha[kt], we[kt], accE, 0, 0, 0);
      float* er = &ering[(s - 1) & 1][0];
      #pragma unroll
      for (int r = 0; r < 4; ++r)
        er[(q * 4 + r) * 16 + c] = accE[r] + bt;
    }

    if (s < TT) {
      // x(s) tile A fragments
      bf16x8 xa[4];
      const bf16x8* xr = reinterpret_cast<const bf16x8*>(&xfrag[rb][0]) + l;
      #pragma unroll
      for (int kt = 0; kt < 4; ++kt) xa[kt] = xr[kt * 64];

      // staging: write x(s+1), issue loads for x(s+2) (pure copies)
      if (stg) {
        if (s + 1 < TT)
          *reinterpret_cast<int4*>(&xfrag[rb ^ 1][xoff]) = xv;
        if (s + 2 < TT)
          xv = *reinterpret_cast<const int4*>(
              ebf + (size_t)sentb[s + 2] * 128 + g * 8);
      }

      // ---- gate GEMM: bias + x@Wih^T + h@Whh^T ----
      f32x4 acc[4];
      #pragma unroll
      for (int tt = 0; tt < 4; ++tt) {
        acc[tt][0] = biasv[tt]; acc[tt][1] = biasv[tt];
        acc[tt][2] = biasv[tt]; acc[tt][3] = biasv[tt];
      }
      #pragma unroll
      for (int kt = 0; kt < 4; ++kt) {
        #pragma unroll
        for (int tt = 0; tt < 4; ++tt)
          acc[tt] = __builtin_amdgcn_mfma_f32_16x16x32_bf16(xa[kt], wx[tt][kt], acc[tt], 0, 0, 0);
      }
      #pragma unroll
      for (int kt = 0; kt < 4; ++kt) {
        #pragma unroll
        for (int tt = 0; tt < 4; ++tt)
          acc[tt] = __builtin_amdgcn_mfma_f32_16x16x32_bf16(ha[kt], wh[tt][kt], acc[tt], 0, 0, 0);
      }

      // ---- cell update: lane-local ----
      unsigned short* hwp = &hfrag[rb ^ 1][hw_off];
      #pragma unroll
      for (int r = 0; r < 4; ++r) {
        float si = sigr(acc[0][r]);
        float sf = sigr(acc[1][r]);
        float tg = tanhr(acc[2][r]);
        float so = sigr(acc[3][r]);
        cst[r] = __fmaf_rn(sf, cst[r], si * tg);
        hwp[r * 8] = f2bf(so * tanhr(cst[r]));
      }
    }

    // ---- Viterbi DP (waves 4-7, lag 2): t = s-2, batch = (w-4)*4+q ----
    if (w >= 4 && s >= 2 && c < KK) {
      const int t_ = s - 2;
      const int b = (w - 4) * 4 + q;
      float Ev = ering[t_ & 1][b * 16 + c];
      float nv;
      if (t_ == 0) {
        nv = Ev;
      } else {
        float4 v0 = *reinterpret_cast<const float4*>(&vit[b * 16]);
        float4 v1 = *reinterpret_cast<const float4*>(&vit[b * 16 + 4]);
        float4 v2 = *reinterpret_cast<const float4*>(&vit[b * 16 + 8]);
        float4 t0 = *reinterpret_cast<const float4*>(&trl[c * 16]);
        float4 t1 = *reinterpret_cast<const float4*>(&trl[c * 16 + 4]);
        float4 t2 = *reinterpret_cast<const float4*>(&trl[c * 16 + 8]);
        float cand[KK] = {v0.x + t0.x, v0.y + t0.y, v0.z + t0.z, v0.w + t0.w,
                          v1.x + t1.x, v1.y + t1.y, v1.z + t1.z, v1.w + t1.w,
                          v2.x + t2.x, v2.y + t2.y, v2.z + t2.z, v2.w + t2.w};
        // max3-tree for value
        float g0 = fmaxf(fmaxf(cand[0], cand[1]), cand[2]);
        float g1 = fmaxf(fmaxf(cand[3], cand[4]), cand[5]);
        float g2 = fmaxf(fmaxf(cand[6], cand[7]), cand[8]);
        float g3 = fmaxf(fmaxf(cand[9], cand[10]), cand[11]);
        float best = fmaxf(fmaxf(g0, g1), fmaxf(g2, g3));
        // first-max index: reverse equality scan
        int bi = 11;
        #pragma unroll
        for (int i = 10; i >= 0; --i) bi = (cand[i] == best) ? i : bi;
        nv = Ev + best;
        if (t_ & 1) bp[(t_ >> 1) * 192 + b * 12 + c] =
                        (unsigned char)(nib | (bi << 4));
        else        nib = bi;
      }
      vit[b * 16 + c] = nv;
    }

    __syncthreads();
  }

  // ---- scores + backtrace (16 parallel chains) ----
  unsigned char* pb = reinterpret_cast<unsigned char*>(hfrag);  // reuse 8 KB
  if (tid < 16) {
    int b = tid;
    float best = vit[b * 16];
    int tag = 0;
    for (int jj = 1; jj < KK; ++jj) {
      float v = vit[b * 16 + jj];
      if (v > best) { best = v; tag = jj; }
    }
    out[bg * 16 + b] = best;                    // scores
    pb[b * 512 + 511] = (unsigned char)tag;
    for (int t_ = TT - 1; t_ >= 1; --t_) {
      unsigned char byte = bp[(t_ >> 1) * 192 + b * 12 + tag];
      tag = (t_ & 1) ? (byte >> 4) & 15 : (byte & 15);
      pb[b * 512 + t_ - 1] = (unsigned char)tag;
    }
  }
  __syncthreads();

  #pragma unroll
  for (int i = 0; i < 16; ++i) {
    int idx = tid + i * 512;
    out[BB + (size_t)bg * 8192 + idx] = (float)pb[idx];
  }
}

// ---------------------------------------------------------------------------
extern "C" void kernel_launch(void* const* d_in, const int* in_sizes, int n_in,
                              void* d_out, int out_size, void* d_ws, size_t ws_size,
                              hipStream_t stream) {
  const int*   sent  = (const int*)d_in[0];
  const float* h0    = (const float*)d_in[1];
  const float* c0    = (const float*)d_in[2];
  const float* embed = (const float*)d_in[3];
  const float* Wih   = (const float*)d_in[4];
  const float* Whh   = (const float*)d_in[5];
  const float* bih   = (const float*)d_in[6];
  const float* bhh   = (const float*)d_in[7];
  const float* Wtag  = (const float*)d_in[8];
  const float* btag  = (const float*)d_in[9];
  const float* trans = (const float*)d_in[10];
  float* out = (float*)d_out;
  unsigned short* ebf = (unsigned short*)d_ws;   // [V][128] bf16, 12.9 MB

  precast_kernel<<<(VV * 16 + 255) / 256, 256, 0, stream>>>(embed, ebf);
  lstm_crf_fused<<<BB / 16, 512, 0, stream>>>(
      sent, ebf, Wih, Whh, bih, bhh, h0, c0, Wtag, btag, trans, out);
}

// Round 9
// 561.022 us; speedup vs baseline: 1.3290x; 1.3290x over previous
//
#include <hip/hip_runtime.h>
#include <hip/hip_bf16.h>

#define BB 128   // batch
#define TT 512   // time
#define EE 100   // embed dim
#define HH 128   // hidden
#define KK 12    // tags
#define VV 50257 // vocab
#define NB 8     // batches per block
#define NBLK 16  // blocks

typedef short bf16x8 __attribute__((ext_vector_type(8)));
typedef float f32x4  __attribute__((ext_vector_type(4)));

__device__ __forceinline__ unsigned short f2bf(float x) {
  __hip_bfloat16 h = __float2bfloat16(x);
  return *reinterpret_cast<unsigned short*>(&h);
}

__device__ __forceinline__ bf16x8 load8_bf(const float* p) {
  float4 a = *reinterpret_cast<const float4*>(p);
  float4 b = *reinterpret_cast<const float4*>(p + 4);
  bf16x8 r;
  r[0] = (short)f2bf(a.x); r[1] = (short)f2bf(a.y);
  r[2] = (short)f2bf(a.z); r[3] = (short)f2bf(a.w);
  r[4] = (short)f2bf(b.x); r[5] = (short)f2bf(b.y);
  r[6] = (short)f2bf(b.z); r[7] = (short)f2bf(b.w);
  return r;
}

__device__ __forceinline__ bf16x8 load8_bf_pad(const float* row, int k0, int n) {
  bf16x8 r;
  #pragma unroll
  for (int i = 0; i < 8; ++i) {
    unsigned short v = 0;
    if (k0 + i < n) v = f2bf(row[k0 + i]);
    r[i] = (short)v;
  }
  return r;
}

// fast sigmoid / tanh: v_exp2 + v_rcp
__device__ __forceinline__ float sigr(float x) {
  float e = __builtin_amdgcn_exp2f(x * -1.44269504f);
  return __builtin_amdgcn_rcpf(1.0f + e);
}
__device__ __forceinline__ float tanhr(float x) {
  float e = __builtin_amdgcn_exp2f(x * -2.88539008f);
  return __fmaf_rn(2.0f, __builtin_amdgcn_rcpf(1.0f + e), -1.0f);
}

// ushort index of (row b, col k) in A-frag-ordered tile (lane-linear)
__device__ __forceinline__ int frag_idx(int b, int k) {
  return ((k >> 5) << 9) + ((b + (((k >> 3) & 3) << 4)) << 3) + (k & 7);
}

// ---------------------------------------------------------------------------
// Kernel 0: one-time precast of embedding table to bf16 [V][128], K-padded.
// ---------------------------------------------------------------------------
__global__ __launch_bounds__(256) void precast_kernel(
    const float* __restrict__ embed, unsigned short* __restrict__ ebf)
{
  int id = blockIdx.x * 256 + threadIdx.x;
  if (id >= VV * 16) return;
  int v = id >> 4, g = id & 15;
  const float* row = embed + (size_t)v * EE;
  bf16x8 o;
  #pragma unroll
  for (int i = 0; i < 8; ++i) {
    int k = g * 8 + i;
    o[i] = (short)((k < EE) ? f2bf(row[k]) : (unsigned short)0);
  }
  *reinterpret_cast<bf16x8*>(ebf + (size_t)id * 8) = o;
}

// ---------------------------------------------------------------------------
// Fused kernel. grid = 16 blocks (8 batches each) x 512 threads (8 waves).
// Batch lb (0..7) lives at MFMA row (lb>>1)*4 + (lb&1)  -> every lane's cell
// update is a uniform 2-iteration loop. x A-frags come straight from the bf16
// embed table (per-lane global gather, prefetched 2 steps ahead). Wave 0:
// emission MFMA (lag 1). Waves 4-7: Viterbi DP (lag 2). 1 barrier/step.
// ---------------------------------------------------------------------------
__global__ __launch_bounds__(512, 2) void lstm_crf_fused(
    const int* __restrict__ sent, const unsigned short* __restrict__ ebf,
    const float* __restrict__ Wih, const float* __restrict__ Whh,
    const float* __restrict__ bih, const float* __restrict__ bhh,
    const float* __restrict__ h0, const float* __restrict__ c0,
    const float* __restrict__ Wtag, const float* __restrict__ btag,
    const float* __restrict__ trans, float* __restrict__ out)
{
  __shared__ unsigned char bp[256 * 96];                   // 24 KB nibble-packed
  __shared__ int sentl[NB * TT];                           // 16 KB sentence ids
  __shared__ __align__(16) unsigned short hfrag[2][2048];  // 8 KB h, frag order
  __shared__ __align__(16) float vit[NB * 16];
  __shared__ __align__(16) float trl[KK * 16];             // trl[j*16+i]=trans[i][j]
  __shared__ __align__(16) float ering[2][NB * 16];        // emission ring

  const int bg  = blockIdx.x;
  const int tid = threadIdx.x;
  const int w   = tid >> 6;         // wave 0..7
  const int l   = tid & 63;
  const int c   = l & 15;           // MFMA col within tile
  const int q   = l >> 4;           // row group
  const int ew  = 16 * w + c;       // this lane's gate column (e)

  // ---- weights: 4 gate-tiles {i,f,g,o} of e-strip [16w,16w+16) ----
  bf16x8 wh[4][4], wx[4][4];
  float biasv[4];
  #pragma unroll
  for (int tt = 0; tt < 4; ++tt) {
    const int gcol = tt * HH + ew;
    biasv[tt] = bih[gcol] + bhh[gcol];
    #pragma unroll
    for (int kt = 0; kt < 4; ++kt) {
      const int k0 = kt * 32 + q * 8;
      wh[tt][kt] = load8_bf(Whh + (size_t)gcol * HH + k0);
      wx[tt][kt] = load8_bf_pad(Wih + (size_t)gcol * EE, k0, EE);
    }
  }

  // ---- cell state: lane (q,c) holds c for lb = q*2+r (rows q*4+r), r=0,1 ----
  float cst[2];
  #pragma unroll
  for (int r = 0; r < 2; ++r)
    cst[r] = c0[(size_t)(bg * NB + q * 2 + r) * HH + ew];

  // ---- emission weight fragments (wave 0) ----
  bf16x8 we[4];
  #pragma unroll
  for (int kt = 0; kt < 4; ++kt) {
    #pragma unroll
    for (int i = 0; i < 8; ++i) we[kt][i] = 0;
  }
  float bt = 0.f;
  if (w == 0 && c < KK) {
    #pragma unroll
    for (int kt = 0; kt < 4; ++kt)
      we[kt] = load8_bf(Wtag + (size_t)c * HH + kt * 32 + q * 8);
    bt = btag[c];
  }

  // ---- zero both h buffers (garbage rows must stay finite/zero) ----
  if (tid < 512) {
    int4 z = {0, 0, 0, 0};
    reinterpret_cast<int4*>(hfrag)[tid] = z;
  }
  // ---- sentence-id table [NB][TT] ----
  #pragma unroll
  for (int i = 0; i < NB; ++i) {
    int idx = tid + i * 512;
    sentl[idx] = sent[(size_t)(bg * NB + (idx >> 9)) * TT + (idx & 511)];
  }
  // ---- transitions (transposed, padded) ----
  if (tid < KK * KK) {
    int i = tid / KK, jj = tid - i * KK;
    trl[jj * 16 + i] = trans[tid];
  }
  __syncthreads();   // zero-pass must complete before h0 fill

  // ---- h0 -> hfrag[0] valid rows ----
  for (int idx = tid; idx < NB * HH; idx += 512) {
    int lb = idx >> 7, k = idx & 127;
    int row = ((lb >> 1) << 2) + (lb & 1);
    hfrag[0][frag_idx(row, k)] = f2bf(h0[(size_t)(bg * NB + lb) * HH + k]);
  }

  // ---- x A-frag gather setup: lane row = c..; sentence row for this lane ----
  const int row  = l & 15;
  const int lbr  = ((row >> 2) << 1) + (row & 1);   // clamp garbage rows to valid
  const int koff = (l >> 4) * 8;                    // ushort offset within x row
  const int* sentr = sent + (size_t)(bg * NB + lbr) * TT;
  bf16x8 xaA[4], xaB[4];
  {
    const bf16x8* s0 = reinterpret_cast<const bf16x8*>(
        ebf + (size_t)sentr[0] * 128 + koff);
    const bf16x8* s1 = reinterpret_cast<const bf16x8*>(
        ebf + (size_t)sentr[1] * 128 + koff);
    #pragma unroll
    for (int kt = 0; kt < 4; ++kt) { xaA[kt] = s0[kt * 4]; xaB[kt] = s1[kt * 4]; }
  }

  const int hw_off = frag_idx(q * 4, ew);
  int nib = 0;
  __syncthreads();

  // ---- main loop, unrolled x2 so the x prefetch double-buffer is static ----
  auto step = [&](int s, bf16x8 (&xcur)[4], bf16x8 (&xnxt)[4]) {
    const int rb = s & 1;
    (void)xnxt;

    bf16x8 ha[4];
    if (s <= TT) {
      const bf16x8* hr = reinterpret_cast<const bf16x8*>(&hfrag[rb][0]) + l;
      #pragma unroll
      for (int kt = 0; kt < 4; ++kt) ha[kt] = hr[kt * 64];
    }

    // wave 0: emissions E(t=s-1) -> ering
    if (w == 0 && s >= 1 && s <= TT) {
      f32x4 accE = {0.f, 0.f, 0.f, 0.f};
      #pragma unroll
      for (int kt = 0; kt < 4; ++kt)
        accE = __builtin_amdgcn_mfma_f32_16x16x32_bf16(ha[kt], we[kt], accE, 0, 0, 0);
      float* er = &ering[(s - 1) & 1][0];
      #pragma unroll
      for (int r = 0; r < 2; ++r)
        er[(q * 2 + r) * 16 + c] = accE[r] + bt;
    }

    if (s < TT) {
      // gate GEMM: bias + x@Wih^T + h@Whh^T
      f32x4 acc[4];
      #pragma unroll
      for (int tt = 0; tt < 4; ++tt) {
        acc[tt][0] = biasv[tt]; acc[tt][1] = biasv[tt];
        acc[tt][2] = biasv[tt]; acc[tt][3] = biasv[tt];
      }
      #pragma unroll
      for (int kt = 0; kt < 4; ++kt) {
        #pragma unroll
        for (int tt = 0; tt < 4; ++tt)
          acc[tt] = __builtin_amdgcn_mfma_f32_16x16x32_bf16(xcur[kt], wx[tt][kt], acc[tt], 0, 0, 0);
      }
      #pragma unroll
      for (int kt = 0; kt < 4; ++kt) {
        #pragma unroll
        for (int tt = 0; tt < 4; ++tt)
          acc[tt] = __builtin_amdgcn_mfma_f32_16x16x32_bf16(ha[kt], wh[tt][kt], acc[tt], 0, 0, 0);
      }

      // prefetch x(s+2) into xcur (consumed two steps from now)
      if (s + 2 < TT) {
        int id = sentl[lbr * TT + s + 2];
        const bf16x8* src = reinterpret_cast<const bf16x8*>(
            ebf + (size_t)id * 128 + koff);
        #pragma unroll
        for (int kt = 0; kt < 4; ++kt) xcur[kt] = src[kt * 4];
      }

      // cell update: lane-local, uniform 2 rows
      unsigned short* hwp = &hfrag[rb ^ 1][hw_off];
      #pragma unroll
      for (int r = 0; r < 2; ++r) {
        float si = sigr(acc[0][r]);
        float sf = sigr(acc[1][r]);
        float tg = tanhr(acc[2][r]);
        float so = sigr(acc[3][r]);
        cst[r] = __fmaf_rn(sf, cst[r], si * tg);
        hwp[r * 8] = f2bf(so * tanhr(cst[r]));
      }
    }

    // Viterbi DP (waves 4-7, lag 2): t = s-2, batch = (w-4)*2+q
    if (w >= 4 && s >= 2 && q < 2 && c < KK) {
      const int t_ = s - 2;
      const int b = (w - 4) * 2 + q;
      float Ev = ering[t_ & 1][b * 16 + c];
      float nv;
      if (t_ == 0) {
        nv = Ev;
      } else {
        float4 v0 = *reinterpret_cast<const float4*>(&vit[b * 16]);
        float4 v1 = *reinterpret_cast<const float4*>(&vit[b * 16 + 4]);
        float4 v2 = *reinterpret_cast<const float4*>(&vit[b * 16 + 8]);
        float4 t0 = *reinterpret_cast<const float4*>(&trl[c * 16]);
        float4 t1 = *reinterpret_cast<const float4*>(&trl[c * 16 + 4]);
        float4 t2 = *reinterpret_cast<const float4*>(&trl[c * 16 + 8]);
        float cand[KK] = {v0.x + t0.x, v0.y + t0.y, v0.z + t0.z, v0.w + t0.w,
                          v1.x + t1.x, v1.y + t1.y, v1.z + t1.z, v1.w + t1.w,
                          v2.x + t2.x, v2.y + t2.y, v2.z + t2.z, v2.w + t2.w};
        float g0 = fmaxf(fmaxf(cand[0], cand[1]), cand[2]);
        float g1 = fmaxf(fmaxf(cand[3], cand[4]), cand[5]);
        float g2 = fmaxf(fmaxf(cand[6], cand[7]), cand[8]);
        float g3 = fmaxf(fmaxf(cand[9], cand[10]), cand[11]);
        float best = fmaxf(fmaxf(g0, g1), fmaxf(g2, g3));
        int bi = 11;
        #pragma unroll
        for (int i = 10; i >= 0; --i) bi = (cand[i] == best) ? i : bi;   // first-max
        nv = Ev + best;
        if (t_ & 1) bp[(t_ >> 1) * 96 + b * 12 + c] =
                        (unsigned char)(nib | (bi << 4));
        else        nib = bi;
      }
      vit[b * 16 + c] = nv;
    }

    __syncthreads();
  };

  for (int s = 0; s < TT + 2; s += 2) {
    step(s, xaA, xaB);
    step(s + 1, xaB, xaA);
  }

  // ---- scores + backtrace (8 parallel chains) ----
  unsigned char* pb = reinterpret_cast<unsigned char*>(hfrag);  // reuse 8 KB
  if (tid < NB) {
    int b = tid;
    float best = vit[b * 16];
    int tag = 0;
    for (int jj = 1; jj < KK; ++jj) {
      float v = vit[b * 16 + jj];
      if (v > best) { best = v; tag = jj; }
    }
    out[bg * NB + b] = best;                    // scores
    pb[b * 512 + 511] = (unsigned char)tag;
    for (int t_ = TT - 1; t_ >= 1; --t_) {
      unsigned char byte = bp[(t_ >> 1) * 96 + b * 12 + tag];
      tag = (t_ & 1) ? (byte >> 4) & 15 : (byte & 15);
      pb[b * 512 + t_ - 1] = (unsigned char)tag;
    }
  }
  __syncthreads();

  #pragma unroll
  for (int i = 0; i < NB; ++i) {
    int idx = tid + i * 512;
    out[BB + (size_t)(bg * NB + (idx >> 9)) * TT + (idx & 511)] = (float)pb[idx];
  }
}

// ---------------------------------------------------------------------------
extern "C" void kernel_launch(void* const* d_in, const int* in_sizes, int n_in,
                              void* d_out, int out_size, void* d_ws, size_t ws_size,
                              hipStream_t stream) {
  const int*   sent  = (const int*)d_in[0];
  const float* h0    = (const float*)d_in[1];
  const float* c0    = (const float*)d_in[2];
  const float* embed = (const float*)d_in[3];
  const float* Wih   = (const float*)d_in[4];
  const float* Whh   = (const float*)d_in[5];
  const float* bih   = (const float*)d_in[6];
  const float* bhh   = (const float*)d_in[7];
  const float* Wtag  = (const float*)d_in[8];
  const float* btag  = (const float*)d_in[9];
  const float* trans = (const float*)d_in[10];
  float* out = (float*)d_out;
  unsigned short* ebf = (unsigned short*)d_ws;   // [V][128] bf16, 12.9 MB

  precast_kernel<<<(VV * 16 + 255) / 256, 256, 0, stream>>>(embed, ebf);
  lstm_crf_fused<<<NBLK, 512, 0, stream>>>(
      sent, ebf, Wih, Whh, bih, bhh, h0, c0, Wtag, btag, trans, out);
}